// Round 14
// baseline (288.420 us; speedup 1.0000x reference)
//
#include <hip/hip_runtime.h>

#define NROWS 32768
#define DIM 256
#define KCODES 1024
#define DECAYF 0.99f
#define EPSF 1e-5f

typedef float f32x4 __attribute__((ext_vector_type(4)));
typedef short short8 __attribute__((ext_vector_type(8)));

// ---------------- workspace layout (bytes), ~52.3 MB ----------------
// xh: 0          xm: 16777216   xl: 33554432          (each 16 MB)
//   (partial[4][1024][256] f32, 4 MB, ALIASES xh after k_distm is done)
// eh: 50331648   em: 50855936   el: 51380224          (each 512 KB)
// keys u64[32768]:   51904512   (256 KB)
// counts int[1024]:  52166656
// offsets int[1024]: 52170752
// cursor int[1024]:  52174848
// bucket int[32768]: 52178944   (128 KB)
// loss_part[8192]:   52310016   (32 KB)
// enorm[1024]:       52342784
// ws_total:          52346880

__device__ inline unsigned short f2bf(float f) {
    unsigned u = __float_as_uint(f);
    return (unsigned short)((u + 0x7FFFu + ((u >> 16) & 1u)) >> 16);
}
__device__ inline float bf2f(unsigned short h) {
    return __uint_as_float(((unsigned)h) << 16);
}

// async global->LDS, 16B per lane; LDS dest = wave-uniform base + lane*16
__device__ __forceinline__ void gload_lds16(const void* g, void* l) {
    __builtin_amdgcn_global_load_lds(
        (const __attribute__((address_space(1))) unsigned int*)g,
        (__attribute__((address_space(3))) unsigned int*)l, 16, 0, 0);
}

// fused: split x+emb into 3 bf16 planes, init keys/counts, enorm (verbatim)
__global__ __launch_bounds__(256) void k_split2(
    const float* __restrict__ x, const float* __restrict__ emb,
    unsigned short* __restrict__ xh, unsigned short* __restrict__ xm,
    unsigned short* __restrict__ xl, unsigned short* __restrict__ eh,
    unsigned short* __restrict__ em, unsigned short* __restrict__ el,
    float* __restrict__ enorm, unsigned long long* __restrict__ keys,
    int* __restrict__ counts) {
    int b = blockIdx.x, t = threadIdx.x;
    if (b < 4224) {
        const float* src;
        unsigned short *ph, *pm, *pl;
        int i;
        if (b < 4096) { src = x; ph = xh; pm = xm; pl = xl; i = b * 256 + t; }
        else { src = emb; ph = eh; pm = em; pl = el; i = (b - 4096) * 256 + t; }
        const float4* xp = (const float4*)src;
        float4 a = xp[i * 2], c = xp[i * 2 + 1];
        float v[8] = {a.x, a.y, a.z, a.w, c.x, c.y, c.z, c.w};
        short8 H, M, L;
#pragma unroll
        for (int u = 0; u < 8; ++u) {
            unsigned short h = f2bf(v[u]);
            float r1 = v[u] - bf2f(h);
            unsigned short m = f2bf(r1);
            float r2 = r1 - bf2f(m);
            unsigned short lo = f2bf(r2);
            H[u] = (short)h; M[u] = (short)m; L[u] = (short)lo;
        }
        *(short8*)&ph[(size_t)i * 8] = H;
        *(short8*)&pm[(size_t)i * 8] = M;
        *(short8*)&pl[(size_t)i * 8] = L;
        if (b < 128) keys[b * 256 + t] = 0xFFFFFFFFFFFFFFFFull;
        else if (b < 132) counts[(b - 128) * 256 + t] = 0;
    } else {
        int blk = b - 4224;
        int w = t >> 6, lane = t & 63;
        int c = blk * 4 + w;
        const float4 v = *(const float4*)&emb[(size_t)c * DIM + lane * 4];
        float s = v.x * v.x + v.y * v.y + v.z * v.z + v.w * v.w;
#pragma unroll
        for (int m = 32; m; m >>= 1) s += __shfl_xor(s, m, 64);
        if (lane == 0) enorm[c] = s;
    }
}

// MFMA distance + fused argmin. 6-term split-bf16 emulated-fp32 GEMM.
// Round-12 structure (128x128 tile, 4 waves, counted-vmcnt phases) with
// el/xl SHARING one LDS buffer: 40 KB total -> 4 blocks/CU (160 KB exact),
// 16 waves/CU. xl is issued after an el-drain barrier at the chunk tail.
// Phases: vmcnt(6) hh | (4) hm | (2) mh+mm | (0) hl | drain, xl, (0) lh.
// Per-(row,code) MFMA order and operands identical to the passing
// round-12 kernel -> bit-identical distances.
__global__ __launch_bounds__(256, 4) void k_distm(
    const unsigned short* __restrict__ xh, const unsigned short* __restrict__ xm,
    const unsigned short* __restrict__ xl, const unsigned short* __restrict__ eh,
    const unsigned short* __restrict__ em, const unsigned short* __restrict__ el,
    const float* __restrict__ enorm, unsigned long long* __restrict__ keys) {
    // buffers: 0=xh, 1=xm, 2=eh, 3=em, 4=el-then-xl   (5 x 8 KB = 40 KB)
    __shared__ unsigned short S[5][4096];

    const int t = threadIdx.x;
    const int l = t & 63, w = t >> 6;
    const int wr = w >> 1, wc = w & 1;
    const int b = blockIdx.x;
    const int logical = (b & 7) * 256 + (b >> 3);  // bijective: 2048 % 8 == 0
    const int brow = (logical >> 3) * 128;
    const int bcol = (logical & 7) * 128;

    f32x4 acc[4][4] = {};

    const int rlane = l & 15;
    const int klane = (l >> 4) * 8;
    const int sg0 = 2 * w, sg1 = 2 * w + 1;
    const size_t ra0 = (size_t)(brow + sg0 * 16 + rlane) * 256 + klane;
    const size_t ra1 = (size_t)(brow + sg1 * 16 + rlane) * 256 + klane;
    const size_t ca0 = (size_t)(bcol + sg0 * 16 + rlane) * 256 + klane;
    const size_t ca1 = (size_t)(bcol + sg1 * 16 + rlane) * 256 + klane;

    for (int s = 0; s < 8; ++s) {
        const int k0 = s * 32;
        __builtin_amdgcn_s_barrier();  // all waves done reading prev chunk
        // 10 loads in consumption order: xh,xh,eh,eh | em,em | xm,xm | el,el
        gload_lds16(&xh[ra0 + k0], &S[0][sg0 * 512]);
        gload_lds16(&xh[ra1 + k0], &S[0][sg1 * 512]);
        gload_lds16(&eh[ca0 + k0], &S[2][sg0 * 512]);
        gload_lds16(&eh[ca1 + k0], &S[2][sg1 * 512]);
        gload_lds16(&em[ca0 + k0], &S[3][sg0 * 512]);
        gload_lds16(&em[ca1 + k0], &S[3][sg1 * 512]);
        gload_lds16(&xm[ra0 + k0], &S[1][sg0 * 512]);
        gload_lds16(&xm[ra1 + k0], &S[1][sg1 * 512]);
        gload_lds16(&el[ca0 + k0], &S[4][sg0 * 512]);
        gload_lds16(&el[ca1 + k0], &S[4][sg1 * 512]);

        short8 ah[4], bh[4], am[4], bm[4], bl[4], al[4];

        asm volatile("s_waitcnt vmcnt(6)" ::: "memory");
        __builtin_amdgcn_s_barrier();   // xh + eh visible
#pragma unroll
        for (int i = 0; i < 4; ++i)
            ah[i] = *(const short8*)&S[0][(wr * 4 + i) * 512 + l * 8];
#pragma unroll
        for (int j = 0; j < 4; ++j)
            bh[j] = *(const short8*)&S[2][(wc * 4 + j) * 512 + l * 8];
        __builtin_amdgcn_s_setprio(1);
#pragma unroll
        for (int i = 0; i < 4; ++i)
#pragma unroll
            for (int j = 0; j < 4; ++j)
                acc[i][j] = __builtin_amdgcn_mfma_f32_16x16x32_bf16(
                    ah[i], bh[j], acc[i][j], 0, 0, 0);
        __builtin_amdgcn_s_setprio(0);

        asm volatile("s_waitcnt vmcnt(4)" ::: "memory");
        __builtin_amdgcn_s_barrier();   // em visible
#pragma unroll
        for (int j = 0; j < 4; ++j)
            bm[j] = *(const short8*)&S[3][(wc * 4 + j) * 512 + l * 8];
        __builtin_amdgcn_s_setprio(1);
#pragma unroll
        for (int i = 0; i < 4; ++i)
#pragma unroll
            for (int j = 0; j < 4; ++j)
                acc[i][j] = __builtin_amdgcn_mfma_f32_16x16x32_bf16(
                    ah[i], bm[j], acc[i][j], 0, 0, 0);
        __builtin_amdgcn_s_setprio(0);

        asm volatile("s_waitcnt vmcnt(2)" ::: "memory");
        __builtin_amdgcn_s_barrier();   // xm visible
#pragma unroll
        for (int i = 0; i < 4; ++i)
            am[i] = *(const short8*)&S[1][(wr * 4 + i) * 512 + l * 8];
        __builtin_amdgcn_s_setprio(1);
#pragma unroll
        for (int i = 0; i < 4; ++i)
#pragma unroll
            for (int j = 0; j < 4; ++j)
                acc[i][j] = __builtin_amdgcn_mfma_f32_16x16x32_bf16(
                    am[i], bh[j], acc[i][j], 0, 0, 0);
#pragma unroll
        for (int i = 0; i < 4; ++i)
#pragma unroll
            for (int j = 0; j < 4; ++j)
                acc[i][j] = __builtin_amdgcn_mfma_f32_16x16x32_bf16(
                    am[i], bm[j], acc[i][j], 0, 0, 0);
        __builtin_amdgcn_s_setprio(0);

        asm volatile("s_waitcnt vmcnt(0)" ::: "memory");
        __builtin_amdgcn_s_barrier();   // el visible
#pragma unroll
        for (int j = 0; j < 4; ++j)
            bl[j] = *(const short8*)&S[4][(wc * 4 + j) * 512 + l * 8];
        __builtin_amdgcn_s_setprio(1);
#pragma unroll
        for (int i = 0; i < 4; ++i)
#pragma unroll
            for (int j = 0; j < 4; ++j)
                acc[i][j] = __builtin_amdgcn_mfma_f32_16x16x32_bf16(
                    ah[i], bl[j], acc[i][j], 0, 0, 0);
        __builtin_amdgcn_s_setprio(0);

        // all waves must finish reading el before xl overwrites S[4]
        asm volatile("s_waitcnt lgkmcnt(0)" ::: "memory");
        __builtin_amdgcn_s_barrier();
        gload_lds16(&xl[ra0 + k0], &S[4][sg0 * 512]);
        gload_lds16(&xl[ra1 + k0], &S[4][sg1 * 512]);
        asm volatile("s_waitcnt vmcnt(0)" ::: "memory");
        __builtin_amdgcn_s_barrier();   // xl visible
#pragma unroll
        for (int i = 0; i < 4; ++i)
            al[i] = *(const short8*)&S[4][(wr * 4 + i) * 512 + l * 8];
        __builtin_amdgcn_s_setprio(1);
#pragma unroll
        for (int i = 0; i < 4; ++i)
#pragma unroll
            for (int j = 0; j < 4; ++j)
                acc[i][j] = __builtin_amdgcn_mfma_f32_16x16x32_bf16(
                    al[i], bh[j], acc[i][j], 0, 0, 0);
        __builtin_amdgcn_s_setprio(0);

        // own ds_reads serviced before signaling loop-top barrier
        asm volatile("s_waitcnt lgkmcnt(0)" ::: "memory");
    }

    float en[4];
    int cidx[4];
#pragma unroll
    for (int j = 0; j < 4; ++j) {
        cidx[j] = bcol + wc * 64 + j * 16 + (l & 15);
        en[j] = enorm[cidx[j]];
    }
#pragma unroll
    for (int i = 0; i < 4; ++i) {
#pragma unroll
        for (int r = 0; r < 4; ++r) {
            float best = 3.0e38f;
            int bi = 0x7FFFFFFF;
#pragma unroll
            for (int j = 0; j < 4; ++j) {
                float d = en[j] - 2.0f * acc[i][j][r];
                if (d < best || (d == best && cidx[j] < bi)) { best = d; bi = cidx[j]; }
            }
#pragma unroll
            for (int m = 1; m < 16; m <<= 1) {
                float d2 = __shfl_xor(best, m, 64);
                int b2 = __shfl_xor(bi, m, 64);
                if (d2 < best || (d2 == best && b2 < bi)) { best = d2; bi = b2; }
            }
            if ((l & 15) == 0) {
                int grow = brow + wr * 64 + i * 16 + (l >> 4) * 4 + r;
                unsigned int fb = __float_as_uint(best);
                unsigned int key32 = (fb & 0x80000000u) ? ~fb : (fb | 0x80000000u);
                atomicMin(&keys[grow],
                          ((unsigned long long)key32 << 32) | (unsigned)bi);
            }
        }
    }
}

// gather quantized rows, straight-through output, loss partials, counts
__global__ __launch_bounds__(256) void k_scatter(const float* __restrict__ x,
                                                 const float* __restrict__ e,
                                                 const unsigned long long* __restrict__ keys,
                                                 float* __restrict__ out_q,
                                                 float* __restrict__ out_tok,
                                                 int* __restrict__ counts,
                                                 float* __restrict__ loss_part) {
    __shared__ float lred[4];
    int w = threadIdx.x >> 6, lane = threadIdx.x & 63;
    int n = blockIdx.x * 4 + w;
    int k = (int)(unsigned int)(keys[n] & 0xFFFFFFFFull);

    size_t xo = (size_t)n * DIM + lane * 4;
    size_t eo = (size_t)k * DIM + lane * 4;
    const float4 xv = *(const float4*)&x[xo];
    const float4 ev = *(const float4*)&e[eo];

    float4 q;
    q.x = xv.x + (ev.x - xv.x);
    q.y = xv.y + (ev.y - xv.y);
    q.z = xv.z + (ev.z - xv.z);
    q.w = xv.w + (ev.w - xv.w);
    *(float4*)&out_q[xo] = q;

    float dx = xv.x - ev.x, dy = xv.y - ev.y, dz = xv.z - ev.z, dw = xv.w - ev.w;
    float ls = dx * dx + dy * dy + dz * dz + dw * dw;
#pragma unroll
    for (int m = 32; m; m >>= 1) ls += __shfl_xor(ls, m, 64);
    if (lane == 0) {
        lred[w] = ls;
        atomicAdd(&counts[k], 1);
        out_tok[n] = (float)k;
    }

    __syncthreads();
    if (threadIdx.x == 0)
        loss_part[blockIdx.x] = lred[0] + lred[1] + lred[2] + lred[3];
}

// fused: loss reduce + EMA cluster size + total, then prefix scan of counts
__global__ __launch_bounds__(1024) void k_mid(const float* __restrict__ cs,
                                              const int* __restrict__ counts,
                                              const float* __restrict__ loss_part,
                                              float* __restrict__ out_loss,
                                              float* __restrict__ out_ncs,
                                              float* __restrict__ ws_total,
                                              int* __restrict__ offsets,
                                              int* __restrict__ cursor) {
    __shared__ float red[1024];
    __shared__ int si[1024];
    int t = threadIdx.x;

    float ls = 0.0f;
    for (int i = t; i < 8192; i += 1024) ls += loss_part[i];
    red[t] = ls;
    __syncthreads();
    for (int s = 512; s; s >>= 1) {
        if (t < s) red[t] += red[t + s];
        __syncthreads();
    }
    if (t == 0) out_loss[0] = red[0] / 8388608.0f;
    __syncthreads();

    float ncs = cs[t] * DECAYF + (1.0f - DECAYF) * (float)counts[t];
    out_ncs[t] = ncs;
    red[t] = ncs;
    __syncthreads();
    for (int s = 512; s; s >>= 1) {
        if (t < s) red[t] += red[t + s];
        __syncthreads();
    }
    if (t == 0) ws_total[0] = red[0];
    __syncthreads();

    int c = counts[t];
    si[t] = c;
    __syncthreads();
    for (int off = 1; off < 1024; off <<= 1) {
        int v = (t >= off) ? si[t - off] : 0;
        __syncthreads();
        si[t] += v;
        __syncthreads();
    }
    int excl = si[t] - c;
    offsets[t] = excl;
    cursor[t] = excl;
}

// group row ids by code
__global__ __launch_bounds__(256) void k_bucket(const unsigned long long* __restrict__ keys,
                                                int* __restrict__ cursor,
                                                int* __restrict__ bucket) {
    int n = blockIdx.x * 256 + threadIdx.x;
    int k = (int)(unsigned int)(keys[n] & 0xFFFFFFFFull);
    int slot = atomicAdd(&cursor[k], 1);
    bucket[slot] = n;
}

// per-(code, seg): partial row-sum with float4 loads, 4 waves x 4-deep ILP.
__global__ __launch_bounds__(256) void k_embpart(
    const float* __restrict__ x, const int* __restrict__ bucket,
    const int* __restrict__ offsets, const int* __restrict__ counts,
    float* __restrict__ partial) {
    __shared__ float lds[4][256];
    int k = blockIdx.x >> 2, s = blockIdx.x & 3;
    int w = threadIdx.x >> 6, lane = threadIdx.x & 63;
    int off = offsets[k], cnt = counts[k];
    int qcnt = (cnt + 3) >> 2;
    int start = off + s * qcnt;
    int lim = s * qcnt + qcnt;
    if (lim > cnt) lim = cnt;
    int end = off + lim;

    f32x4 acc = {0.0f, 0.0f, 0.0f, 0.0f};
    int i = start + w;
    for (; i + 12 < end; i += 16) {
        int r0 = bucket[i], r1 = bucket[i + 4], r2 = bucket[i + 8], r3 = bucket[i + 12];
        f32x4 v0 = *(const f32x4*)&x[(size_t)r0 * DIM + lane * 4];
        f32x4 v1 = *(const f32x4*)&x[(size_t)r1 * DIM + lane * 4];
        f32x4 v2 = *(const f32x4*)&x[(size_t)r2 * DIM + lane * 4];
        f32x4 v3 = *(const f32x4*)&x[(size_t)r3 * DIM + lane * 4];
        acc += v0; acc += v1; acc += v2; acc += v3;
    }
    for (; i < end; i += 4)
        acc += *(const f32x4*)&x[(size_t)bucket[i] * DIM + lane * 4];

    *(f32x4*)&lds[w][lane * 4] = acc;
    __syncthreads();
    int d = threadIdx.x;
    float sum = lds[0][d] + lds[1][d] + lds[2][d] + lds[3][d];
    partial[((size_t)s * KCODES + k) * DIM + d] = sum;
}

// combine 4 partials (fixed order) + EMA avg + normalized embedding
__global__ __launch_bounds__(256) void k_embfin2(
    const float* __restrict__ partial, const float* __restrict__ avg,
    const float* __restrict__ out_ncs, const float* __restrict__ ws_total,
    float* __restrict__ out_emb, float* __restrict__ out_avg) {
    int k = blockIdx.x, d = threadIdx.x;
    size_t o = (size_t)k * DIM + d;
    float sum = partial[(0 * KCODES + k) * DIM + d]
              + partial[(1 * KCODES + k) * DIM + d]
              + partial[(2 * KCODES + k) * DIM + d]
              + partial[(3 * KCODES + k) * DIM + d];

    float total = ws_total[0];
    float ncs = out_ncs[k];
    float normalized = (ncs + EPSF) / (total + (float)KCODES * EPSF) * total;

    float na = avg[o] * DECAYF + (1.0f - DECAYF) * sum;
    out_avg[o] = na;
    out_emb[o] = na / normalized;
}

extern "C" void kernel_launch(void* const* d_in, const int* in_sizes, int n_in,
                              void* d_out, int out_size, void* d_ws, size_t ws_size,
                              hipStream_t stream) {
    const float* x   = (const float*)d_in[0];
    const float* emb = (const float*)d_in[1];
    const float* cs  = (const float*)d_in[2];
    const float* avg = (const float*)d_in[3];

    float* out      = (float*)d_out;
    float* out_q    = out;
    float* out_tok  = out + 8388608;
    float* out_loss = out + 8421376;
    float* out_emb  = out + 8421377;
    float* out_ncs  = out + 8683521;
    float* out_avg  = out + 8684545;

    char* ws = (char*)d_ws;
    unsigned short* xh = (unsigned short*)(ws + 0);
    unsigned short* xm = (unsigned short*)(ws + 16777216);
    unsigned short* xl = (unsigned short*)(ws + 33554432);
    float* partial   = (float*)(ws + 0);   // aliases xh (dead after k_distm)
    unsigned short* eh = (unsigned short*)(ws + 50331648);
    unsigned short* em = (unsigned short*)(ws + 50855936);
    unsigned short* el = (unsigned short*)(ws + 51380224);
    unsigned long long* keys = (unsigned long long*)(ws + 51904512);
    int* counts      = (int*)(ws + 52166656);
    int* offsets     = (int*)(ws + 52170752);
    int* cursor      = (int*)(ws + 52174848);
    int* bucket      = (int*)(ws + 52178944);
    float* loss_part = (float*)(ws + 52310016);
    float* enorm     = (float*)(ws + 52342784);
    float* ws_total  = (float*)(ws + 52346880);

    k_split2<<<4480, 256, 0, stream>>>(x, emb, xh, xm, xl, eh, em, el,
                                       enorm, keys, counts);
    k_distm<<<2048, 256, 0, stream>>>(xh, xm, xl, eh, em, el, enorm, keys);
    k_scatter<<<NROWS / 4, 256, 0, stream>>>(x, emb, keys, out_q, out_tok,
                                             counts, loss_part);
    k_mid<<<1, 1024, 0, stream>>>(cs, counts, loss_part, out_loss, out_ncs,
                                  ws_total, offsets, cursor);
    k_bucket<<<NROWS / 256, 256, 0, stream>>>(keys, cursor, bucket);
    k_embpart<<<KCODES * 4, 256, 0, stream>>>(x, bucket, offsets, counts,
                                              partial);
    k_embfin2<<<KCODES, 256, 0, stream>>>(partial, avg, out_ncs, ws_total,
                                          out_emb, out_avg);
}

// Round 15
// 203.537 us; speedup vs baseline: 1.4170x; 1.4170x over previous
//
#include <hip/hip_runtime.h>

#define NROWS 32768
#define DIM 256
#define KCODES 1024
#define DECAYF 0.99f
#define EPSF 1e-5f

typedef float f32x4 __attribute__((ext_vector_type(4)));
typedef short short8 __attribute__((ext_vector_type(8)));

// ---------------- workspace layout (bytes), ~52.3 MB ----------------
// xh: 0          xm: 16777216   xl: 33554432          (each 16 MB)
//   (partial[4][1024][256] f32, 4 MB, ALIASES xh after k_distm is done)
// eh: 50331648   em: 50855936   el: 51380224          (each 512 KB)
// keys u64[32768]:   51904512   (256 KB)
// counts int[1024]:  52166656
// offsets int[1024]: 52170752
// cursor int[1024]:  52174848
// bucket int[32768]: 52178944   (128 KB)
// loss_part[8192]:   52310016   (32 KB)
// enorm[1024]:       52342784
// ws_total:          52346880

__device__ inline unsigned short f2bf(float f) {
    unsigned u = __float_as_uint(f);
    return (unsigned short)((u + 0x7FFFu + ((u >> 16) & 1u)) >> 16);
}
__device__ inline float bf2f(unsigned short h) {
    return __uint_as_float(((unsigned)h) << 16);
}

// async global->LDS, 16B per lane; LDS dest = wave-uniform base + lane*16
__device__ __forceinline__ void gload_lds16(const void* g, void* l) {
    __builtin_amdgcn_global_load_lds(
        (const __attribute__((address_space(1))) unsigned int*)g,
        (__attribute__((address_space(3))) unsigned int*)l, 16, 0, 0);
}

// fused: split x+emb into 3 bf16 planes, init keys/counts, enorm (verbatim)
__global__ __launch_bounds__(256) void k_split2(
    const float* __restrict__ x, const float* __restrict__ emb,
    unsigned short* __restrict__ xh, unsigned short* __restrict__ xm,
    unsigned short* __restrict__ xl, unsigned short* __restrict__ eh,
    unsigned short* __restrict__ em, unsigned short* __restrict__ el,
    float* __restrict__ enorm, unsigned long long* __restrict__ keys,
    int* __restrict__ counts) {
    int b = blockIdx.x, t = threadIdx.x;
    if (b < 4224) {
        const float* src;
        unsigned short *ph, *pm, *pl;
        int i;
        if (b < 4096) { src = x; ph = xh; pm = xm; pl = xl; i = b * 256 + t; }
        else { src = emb; ph = eh; pm = em; pl = el; i = (b - 4096) * 256 + t; }
        const float4* xp = (const float4*)src;
        float4 a = xp[i * 2], c = xp[i * 2 + 1];
        float v[8] = {a.x, a.y, a.z, a.w, c.x, c.y, c.z, c.w};
        short8 H, M, L;
#pragma unroll
        for (int u = 0; u < 8; ++u) {
            unsigned short h = f2bf(v[u]);
            float r1 = v[u] - bf2f(h);
            unsigned short m = f2bf(r1);
            float r2 = r1 - bf2f(m);
            unsigned short lo = f2bf(r2);
            H[u] = (short)h; M[u] = (short)m; L[u] = (short)lo;
        }
        *(short8*)&ph[(size_t)i * 8] = H;
        *(short8*)&pm[(size_t)i * 8] = M;
        *(short8*)&pl[(size_t)i * 8] = L;
        if (b < 128) keys[b * 256 + t] = 0xFFFFFFFFFFFFFFFFull;
        else if (b < 132) counts[(b - 128) * 256 + t] = 0;
    } else {
        int blk = b - 4224;
        int w = t >> 6, lane = t & 63;
        int c = blk * 4 + w;
        const float4 v = *(const float4*)&emb[(size_t)c * DIM + lane * 4];
        float s = v.x * v.x + v.y * v.y + v.z * v.z + v.w * v.w;
#pragma unroll
        for (int m = 32; m; m >>= 1) s += __shfl_xor(s, m, 64);
        if (lane == 0) enorm[c] = s;
    }
}

// MFMA distance + fused argmin. 6-term split-bf16 emulated-fp32 GEMM.
// Round-12 phased structure; xl SHARES eh's LDS buffer S[2] (eh fragments
// are register-resident after phase 1). 40 KB LDS -> runtime occupancy
// 4 blocks/CU (LDS-limited), launch_bounds(256,3) so the allocator keeps
// the proven ~84-VGPR no-spill allocation (rounds 13/14 lesson: asking the
// allocator for 4 waves/EU squeezes to 64 VGPR and spills to scratch).
// Phases: vmcnt(6) hh | (4) hm + issue xl | (4) mh+mm | (2) hl | (0) lh.
// MFMA order and operands bit-identical to the passing round-12 kernel.
__global__ __launch_bounds__(256, 3) void k_distm(
    const unsigned short* __restrict__ xh, const unsigned short* __restrict__ xm,
    const unsigned short* __restrict__ xl, const unsigned short* __restrict__ eh,
    const unsigned short* __restrict__ em, const unsigned short* __restrict__ el,
    const float* __restrict__ enorm, unsigned long long* __restrict__ keys) {
    // buffers: 0=xh, 1=xm, 2=eh-then-xl, 3=em, 4=el   (5 x 8 KB = 40 KB)
    __shared__ unsigned short S[5][4096];

    const int t = threadIdx.x;
    const int l = t & 63, w = t >> 6;
    const int wr = w >> 1, wc = w & 1;
    const int b = blockIdx.x;
    const int logical = (b & 7) * 256 + (b >> 3);  // bijective: 2048 % 8 == 0
    const int brow = (logical >> 3) * 128;
    const int bcol = (logical & 7) * 128;

    f32x4 acc[4][4] = {};

    const int rlane = l & 15;
    const int klane = (l >> 4) * 8;
    const int sg0 = 2 * w, sg1 = 2 * w + 1;
    const size_t ra0 = (size_t)(brow + sg0 * 16 + rlane) * 256 + klane;
    const size_t ra1 = (size_t)(brow + sg1 * 16 + rlane) * 256 + klane;
    const size_t ca0 = (size_t)(bcol + sg0 * 16 + rlane) * 256 + klane;
    const size_t ca1 = (size_t)(bcol + sg1 * 16 + rlane) * 256 + klane;

    for (int s = 0; s < 8; ++s) {
        const int k0 = s * 32;
        __builtin_amdgcn_s_barrier();  // all waves done reading prev chunk
        // 10 loads in consumption order: xh,xh,eh,eh | em,em | xm,xm | el,el
        gload_lds16(&xh[ra0 + k0], &S[0][sg0 * 512]);
        gload_lds16(&xh[ra1 + k0], &S[0][sg1 * 512]);
        gload_lds16(&eh[ca0 + k0], &S[2][sg0 * 512]);
        gload_lds16(&eh[ca1 + k0], &S[2][sg1 * 512]);
        gload_lds16(&em[ca0 + k0], &S[3][sg0 * 512]);
        gload_lds16(&em[ca1 + k0], &S[3][sg1 * 512]);
        gload_lds16(&xm[ra0 + k0], &S[1][sg0 * 512]);
        gload_lds16(&xm[ra1 + k0], &S[1][sg1 * 512]);
        gload_lds16(&el[ca0 + k0], &S[4][sg0 * 512]);
        gload_lds16(&el[ca1 + k0], &S[4][sg1 * 512]);

        short8 ah[4], bh[4], am[4], bm[4], bl[4], al[4];

        asm volatile("s_waitcnt vmcnt(6)" ::: "memory");
        __builtin_amdgcn_s_barrier();   // xh + eh visible
#pragma unroll
        for (int i = 0; i < 4; ++i)
            ah[i] = *(const short8*)&S[0][(wr * 4 + i) * 512 + l * 8];
#pragma unroll
        for (int j = 0; j < 4; ++j)
            bh[j] = *(const short8*)&S[2][(wc * 4 + j) * 512 + l * 8];
        __builtin_amdgcn_s_setprio(1);
#pragma unroll
        for (int i = 0; i < 4; ++i)
#pragma unroll
            for (int j = 0; j < 4; ++j)
                acc[i][j] = __builtin_amdgcn_mfma_f32_16x16x32_bf16(
                    ah[i], bh[j], acc[i][j], 0, 0, 0);
        __builtin_amdgcn_s_setprio(0);
        // this wave's S[2] (eh) reads are retired before the next barrier
        asm volatile("s_waitcnt lgkmcnt(0)" ::: "memory");

        asm volatile("s_waitcnt vmcnt(4)" ::: "memory");
        __builtin_amdgcn_s_barrier();   // em visible; ALL waves done with eh
        // xl reuses S[2]; its latency hides under phases hm, mh+mm, hl
        gload_lds16(&xl[ra0 + k0], &S[2][sg0 * 512]);
        gload_lds16(&xl[ra1 + k0], &S[2][sg1 * 512]);
#pragma unroll
        for (int j = 0; j < 4; ++j)
            bm[j] = *(const short8*)&S[3][(wc * 4 + j) * 512 + l * 8];
        __builtin_amdgcn_s_setprio(1);
#pragma unroll
        for (int i = 0; i < 4; ++i)
#pragma unroll
            for (int j = 0; j < 4; ++j)
                acc[i][j] = __builtin_amdgcn_mfma_f32_16x16x32_bf16(
                    ah[i], bm[j], acc[i][j], 0, 0, 0);
        __builtin_amdgcn_s_setprio(0);

        asm volatile("s_waitcnt vmcnt(4)" ::: "memory");
        __builtin_amdgcn_s_barrier();   // xm visible (outstanding: el,el,xl,xl)
#pragma unroll
        for (int i = 0; i < 4; ++i)
            am[i] = *(const short8*)&S[1][(wr * 4 + i) * 512 + l * 8];
        __builtin_amdgcn_s_setprio(1);
#pragma unroll
        for (int i = 0; i < 4; ++i)
#pragma unroll
            for (int j = 0; j < 4; ++j)
                acc[i][j] = __builtin_amdgcn_mfma_f32_16x16x32_bf16(
                    am[i], bh[j], acc[i][j], 0, 0, 0);
#pragma unroll
        for (int i = 0; i < 4; ++i)
#pragma unroll
            for (int j = 0; j < 4; ++j)
                acc[i][j] = __builtin_amdgcn_mfma_f32_16x16x32_bf16(
                    am[i], bm[j], acc[i][j], 0, 0, 0);
        __builtin_amdgcn_s_setprio(0);

        asm volatile("s_waitcnt vmcnt(2)" ::: "memory");
        __builtin_amdgcn_s_barrier();   // el visible (outstanding: xl,xl)
#pragma unroll
        for (int j = 0; j < 4; ++j)
            bl[j] = *(const short8*)&S[4][(wc * 4 + j) * 512 + l * 8];
        __builtin_amdgcn_s_setprio(1);
#pragma unroll
        for (int i = 0; i < 4; ++i)
#pragma unroll
            for (int j = 0; j < 4; ++j)
                acc[i][j] = __builtin_amdgcn_mfma_f32_16x16x32_bf16(
                    ah[i], bl[j], acc[i][j], 0, 0, 0);
        __builtin_amdgcn_s_setprio(0);

        asm volatile("s_waitcnt vmcnt(0)" ::: "memory");
        __builtin_amdgcn_s_barrier();   // xl visible in S[2]
#pragma unroll
        for (int i = 0; i < 4; ++i)
            al[i] = *(const short8*)&S[2][(wr * 4 + i) * 512 + l * 8];
        __builtin_amdgcn_s_setprio(1);
#pragma unroll
        for (int i = 0; i < 4; ++i)
#pragma unroll
            for (int j = 0; j < 4; ++j)
                acc[i][j] = __builtin_amdgcn_mfma_f32_16x16x32_bf16(
                    al[i], bh[j], acc[i][j], 0, 0, 0);
        __builtin_amdgcn_s_setprio(0);

        // own ds_reads serviced before signaling loop-top barrier
        asm volatile("s_waitcnt lgkmcnt(0)" ::: "memory");
    }

    float en[4];
    int cidx[4];
#pragma unroll
    for (int j = 0; j < 4; ++j) {
        cidx[j] = bcol + wc * 64 + j * 16 + (l & 15);
        en[j] = enorm[cidx[j]];
    }
#pragma unroll
    for (int i = 0; i < 4; ++i) {
#pragma unroll
        for (int r = 0; r < 4; ++r) {
            float best = 3.0e38f;
            int bi = 0x7FFFFFFF;
#pragma unroll
            for (int j = 0; j < 4; ++j) {
                float d = en[j] - 2.0f * acc[i][j][r];
                if (d < best || (d == best && cidx[j] < bi)) { best = d; bi = cidx[j]; }
            }
#pragma unroll
            for (int m = 1; m < 16; m <<= 1) {
                float d2 = __shfl_xor(best, m, 64);
                int b2 = __shfl_xor(bi, m, 64);
                if (d2 < best || (d2 == best && b2 < bi)) { best = d2; bi = b2; }
            }
            if ((l & 15) == 0) {
                int grow = brow + wr * 64 + i * 16 + (l >> 4) * 4 + r;
                unsigned int fb = __float_as_uint(best);
                unsigned int key32 = (fb & 0x80000000u) ? ~fb : (fb | 0x80000000u);
                atomicMin(&keys[grow],
                          ((unsigned long long)key32 << 32) | (unsigned)bi);
            }
        }
    }
}

// gather quantized rows, straight-through output, loss partials, counts
__global__ __launch_bounds__(256) void k_scatter(const float* __restrict__ x,
                                                 const float* __restrict__ e,
                                                 const unsigned long long* __restrict__ keys,
                                                 float* __restrict__ out_q,
                                                 float* __restrict__ out_tok,
                                                 int* __restrict__ counts,
                                                 float* __restrict__ loss_part) {
    __shared__ float lred[4];
    int w = threadIdx.x >> 6, lane = threadIdx.x & 63;
    int n = blockIdx.x * 4 + w;
    int k = (int)(unsigned int)(keys[n] & 0xFFFFFFFFull);

    size_t xo = (size_t)n * DIM + lane * 4;
    size_t eo = (size_t)k * DIM + lane * 4;
    const float4 xv = *(const float4*)&x[xo];
    const float4 ev = *(const float4*)&e[eo];

    float4 q;
    q.x = xv.x + (ev.x - xv.x);
    q.y = xv.y + (ev.y - xv.y);
    q.z = xv.z + (ev.z - xv.z);
    q.w = xv.w + (ev.w - xv.w);
    *(float4*)&out_q[xo] = q;

    float dx = xv.x - ev.x, dy = xv.y - ev.y, dz = xv.z - ev.z, dw = xv.w - ev.w;
    float ls = dx * dx + dy * dy + dz * dz + dw * dw;
#pragma unroll
    for (int m = 32; m; m >>= 1) ls += __shfl_xor(ls, m, 64);
    if (lane == 0) {
        lred[w] = ls;
        atomicAdd(&counts[k], 1);
        out_tok[n] = (float)k;
    }

    __syncthreads();
    if (threadIdx.x == 0)
        loss_part[blockIdx.x] = lred[0] + lred[1] + lred[2] + lred[3];
}

// fused: loss reduce + EMA cluster size + total, then prefix scan of counts
__global__ __launch_bounds__(1024) void k_mid(const float* __restrict__ cs,
                                              const int* __restrict__ counts,
                                              const float* __restrict__ loss_part,
                                              float* __restrict__ out_loss,
                                              float* __restrict__ out_ncs,
                                              float* __restrict__ ws_total,
                                              int* __restrict__ offsets,
                                              int* __restrict__ cursor) {
    __shared__ float red[1024];
    __shared__ int si[1024];
    int t = threadIdx.x;

    float ls = 0.0f;
    for (int i = t; i < 8192; i += 1024) ls += loss_part[i];
    red[t] = ls;
    __syncthreads();
    for (int s = 512; s; s >>= 1) {
        if (t < s) red[t] += red[t + s];
        __syncthreads();
    }
    if (t == 0) out_loss[0] = red[0] / 8388608.0f;
    __syncthreads();

    float ncs = cs[t] * DECAYF + (1.0f - DECAYF) * (float)counts[t];
    out_ncs[t] = ncs;
    red[t] = ncs;
    __syncthreads();
    for (int s = 512; s; s >>= 1) {
        if (t < s) red[t] += red[t + s];
        __syncthreads();
    }
    if (t == 0) ws_total[0] = red[0];
    __syncthreads();

    int c = counts[t];
    si[t] = c;
    __syncthreads();
    for (int off = 1; off < 1024; off <<= 1) {
        int v = (t >= off) ? si[t - off] : 0;
        __syncthreads();
        si[t] += v;
        __syncthreads();
    }
    int excl = si[t] - c;
    offsets[t] = excl;
    cursor[t] = excl;
}

// group row ids by code
__global__ __launch_bounds__(256) void k_bucket(const unsigned long long* __restrict__ keys,
                                                int* __restrict__ cursor,
                                                int* __restrict__ bucket) {
    int n = blockIdx.x * 256 + threadIdx.x;
    int k = (int)(unsigned int)(keys[n] & 0xFFFFFFFFull);
    int slot = atomicAdd(&cursor[k], 1);
    bucket[slot] = n;
}

// per-(code, seg): partial row-sum with float4 loads, 4 waves x 4-deep ILP.
__global__ __launch_bounds__(256) void k_embpart(
    const float* __restrict__ x, const int* __restrict__ bucket,
    const int* __restrict__ offsets, const int* __restrict__ counts,
    float* __restrict__ partial) {
    __shared__ float lds[4][256];
    int k = blockIdx.x >> 2, s = blockIdx.x & 3;
    int w = threadIdx.x >> 6, lane = threadIdx.x & 63;
    int off = offsets[k], cnt = counts[k];
    int qcnt = (cnt + 3) >> 2;
    int start = off + s * qcnt;
    int lim = s * qcnt + qcnt;
    if (lim > cnt) lim = cnt;
    int end = off + lim;

    f32x4 acc = {0.0f, 0.0f, 0.0f, 0.0f};
    int i = start + w;
    for (; i + 12 < end; i += 16) {
        int r0 = bucket[i], r1 = bucket[i + 4], r2 = bucket[i + 8], r3 = bucket[i + 12];
        f32x4 v0 = *(const f32x4*)&x[(size_t)r0 * DIM + lane * 4];
        f32x4 v1 = *(const f32x4*)&x[(size_t)r1 * DIM + lane * 4];
        f32x4 v2 = *(const f32x4*)&x[(size_t)r2 * DIM + lane * 4];
        f32x4 v3 = *(const f32x4*)&x[(size_t)r3 * DIM + lane * 4];
        acc += v0; acc += v1; acc += v2; acc += v3;
    }
    for (; i < end; i += 4)
        acc += *(const f32x4*)&x[(size_t)bucket[i] * DIM + lane * 4];

    *(f32x4*)&lds[w][lane * 4] = acc;
    __syncthreads();
    int d = threadIdx.x;
    float sum = lds[0][d] + lds[1][d] + lds[2][d] + lds[3][d];
    partial[((size_t)s * KCODES + k) * DIM + d] = sum;
}

// combine 4 partials (fixed order) + EMA avg + normalized embedding
__global__ __launch_bounds__(256) void k_embfin2(
    const float* __restrict__ partial, const float* __restrict__ avg,
    const float* __restrict__ out_ncs, const float* __restrict__ ws_total,
    float* __restrict__ out_emb, float* __restrict__ out_avg) {
    int k = blockIdx.x, d = threadIdx.x;
    size_t o = (size_t)k * DIM + d;
    float sum = partial[(0 * KCODES + k) * DIM + d]
              + partial[(1 * KCODES + k) * DIM + d]
              + partial[(2 * KCODES + k) * DIM + d]
              + partial[(3 * KCODES + k) * DIM + d];

    float total = ws_total[0];
    float ncs = out_ncs[k];
    float normalized = (ncs + EPSF) / (total + (float)KCODES * EPSF) * total;

    float na = avg[o] * DECAYF + (1.0f - DECAYF) * sum;
    out_avg[o] = na;
    out_emb[o] = na / normalized;
}

extern "C" void kernel_launch(void* const* d_in, const int* in_sizes, int n_in,
                              void* d_out, int out_size, void* d_ws, size_t ws_size,
                              hipStream_t stream) {
    const float* x   = (const float*)d_in[0];
    const float* emb = (const float*)d_in[1];
    const float* cs  = (const float*)d_in[2];
    const float* avg = (const float*)d_in[3];

    float* out      = (float*)d_out;
    float* out_q    = out;
    float* out_tok  = out + 8388608;
    float* out_loss = out + 8421376;
    float* out_emb  = out + 8421377;
    float* out_ncs  = out + 8683521;
    float* out_avg  = out + 8684545;

    char* ws = (char*)d_ws;
    unsigned short* xh = (unsigned short*)(ws + 0);
    unsigned short* xm = (unsigned short*)(ws + 16777216);
    unsigned short* xl = (unsigned short*)(ws + 33554432);
    float* partial   = (float*)(ws + 0);   // aliases xh (dead after k_distm)
    unsigned short* eh = (unsigned short*)(ws + 50331648);
    unsigned short* em = (unsigned short*)(ws + 50855936);
    unsigned short* el = (unsigned short*)(ws + 51380224);
    unsigned long long* keys = (unsigned long long*)(ws + 51904512);
    int* counts      = (int*)(ws + 52166656);
    int* offsets     = (int*)(ws + 52170752);
    int* cursor      = (int*)(ws + 52174848);
    int* bucket      = (int*)(ws + 52178944);
    float* loss_part = (float*)(ws + 52310016);
    float* enorm     = (float*)(ws + 52342784);
    float* ws_total  = (float*)(ws + 52346880);

    k_split2<<<4480, 256, 0, stream>>>(x, emb, xh, xm, xl, eh, em, el,
                                       enorm, keys, counts);
    k_distm<<<2048, 256, 0, stream>>>(xh, xm, xl, eh, em, el, enorm, keys);
    k_scatter<<<NROWS / 4, 256, 0, stream>>>(x, emb, keys, out_q, out_tok,
                                             counts, loss_part);
    k_mid<<<1, 1024, 0, stream>>>(cs, counts, loss_part, out_loss, out_ncs,
                                  ws_total, offsets, cursor);
    k_bucket<<<NROWS / 256, 256, 0, stream>>>(keys, cursor, bucket);
    k_embpart<<<KCODES * 4, 256, 0, stream>>>(x, bucket, offsets, counts,
                                              partial);
    k_embfin2<<<KCODES, 256, 0, stream>>>(partial, avg, out_ncs, ws_total,
                                          out_emb, out_avg);
}